// Round 18
// baseline (162.083 us; speedup 1.0000x reference)
//
#include <hip/hip_runtime.h>

typedef __bf16 bf16;
typedef __bf16 bf16x8 __attribute__((ext_vector_type(8)));
typedef float f32x4 __attribute__((ext_vector_type(4)));

__device__ __forceinline__ f32x4 mfma16(bf16x8 a, bf16x8 b, f32x4 c) {
  return __builtin_amdgcn_mfma_f32_16x16x32_bf16(a, b, c, 0, 0, 0);
}
__device__ __forceinline__ void gload16(const bf16* g, bf16* l) {
  __builtin_amdgcn_global_load_lds((const __attribute__((address_space(1))) unsigned int*)g,
                                   (__attribute__((address_space(3))) unsigned int*)l, 16, 0, 0);
}

// ------- fused prep: x f32->bf16 (0..2047), weight transpose (2048..3071),
//         bias concat (3072..3083), lag rank-sort (3084..3147). grid 3148 -------
__global__ __launch_bounds__(256) void prep_kernel(
    const float* __restrict__ x, const float* __restrict__ wq,
    const float* __restrict__ wk, const float* __restrict__ wv,
    const float* __restrict__ wo, const float* __restrict__ bq,
    const float* __restrict__ bk, const float* __restrict__ bv,
    const int* __restrict__ lag,
    bf16* __restrict__ xb, bf16* __restrict__ wqkvt, bf16* __restrict__ wot,
    float* __restrict__ bqkv, int* __restrict__ perm, int* __restrict__ slag,
    int* __restrict__ rank) {
  int blk = blockIdx.x;
  int tid = threadIdx.x;
  if (blk < 2048) {
    int i = blk * 256 + tid;
    const float4* p = (const float4*)x + (size_t)i * 2;
    float4 f0 = p[0], f1 = p[1];
    bf16x8 o;
    o[0] = (bf16)f0.x; o[1] = (bf16)f0.y; o[2] = (bf16)f0.z; o[3] = (bf16)f0.w;
    o[4] = (bf16)f1.x; o[5] = (bf16)f1.y; o[6] = (bf16)f1.z; o[7] = (bf16)f1.w;
    *((bf16x8*)xb + i) = o;
    return;
  }
  if (blk >= 3084) {
    // deterministic stable rank sort of lag
    __shared__ int l[2048];
    for (int i = tid; i < 2048; i += 256) l[i] = lag[i];
    __syncthreads();
    int i = (blk - 3084) * 32 + (tid >> 3);
    int s = tid & 7;
    int vi = l[i];
    int cnt = 0;
    for (int j = s * 256; j < s * 256 + 256; j += 4) {
      int4 vj = *(const int4*)&l[j];
      cnt += (vj.x < vi || (vj.x == vi && (j + 0) < i));
      cnt += (vj.y < vi || (vj.y == vi && (j + 1) < i));
      cnt += (vj.z < vi || (vj.z == vi && (j + 2) < i));
      cnt += (vj.w < vi || (vj.w == vi && (j + 3) < i));
    }
    cnt += __shfl_xor(cnt, 1);
    cnt += __shfl_xor(cnt, 2);
    cnt += __shfl_xor(cnt, 4);
    if (s == 0) { perm[cnt] = i; slag[cnt] = vi; rank[i] = cnt; }
    return;
  }
  if (blk >= 3072) {
    int i = (blk - 3072) * 256 + tid;
    if (i < 1024) bqkv[i] = bq[i];
    else if (i < 2048) bqkv[i] = bk[i - 1024];
    else if (i < 3072) bqkv[i] = bv[i - 2048];
    return;
  }
  __shared__ float t[64][68];
  int sub = blk - 2048;
  int wsel = sub >> 8;
  sub &= 255;
  const float* in = wsel == 0 ? wq : wsel == 1 ? wk : wsel == 2 ? wv : wo;
  bf16* out = (wsel == 3) ? wot : (wqkvt + (size_t)wsel * (1u << 20));
  int bx = sub & 15;
  int by = sub >> 4;
  int r = tid >> 2, p = tid & 3;
  const float* src = in + (size_t)(by * 64 + r) * 1024 + bx * 64 + p * 16;
#pragma unroll
  for (int j = 0; j < 16; j += 4)
    *(float4*)&t[r][p * 16 + j] = *(const float4*)(src + j);
  __syncthreads();
  int n = tid >> 2, sp = tid & 3;
  bf16 tmp[16];
#pragma unroll
  for (int j = 0; j < 16; ++j) tmp[j] = (bf16)t[sp * 16 + j][n];
  bf16* dst = out + (size_t)(bx * 64 + n) * 1024 + by * 64 + sp * 16;
  *(bf16x8*)dst = *(bf16x8*)&tmp[0];
  *(bf16x8*)(dst + 8) = *(bf16x8*)&tmp[8];
}

// ---- V transpose sorted: vt[(b*16+h)*64 + d][ss] = V[b][perm[ss]][h*64+d] ----
__global__ __launch_bounds__(256) void transpose_v_kernel(const bf16* __restrict__ qkv,
                                                          const int* __restrict__ perm,
                                                          bf16* __restrict__ vt) {
  __shared__ bf16 t[64][72];
  int blk = blockIdx.x;
  int st = blk & 31, h = (blk >> 5) & 15, b = blk >> 9;
  int tid = threadIdx.x;
  int r = tid >> 2, p = tid & 3;
  int src_s = perm[st * 64 + r];
  const bf16* src = qkv + (size_t)(b * 2048 + src_s) * 3072 + 2048 + h * 64 + p * 16;
  *(bf16x8*)&t[r][p * 16] = *(const bf16x8*)src;
  *(bf16x8*)&t[r][p * 16 + 8] = *(const bf16x8*)(src + 8);
  __syncthreads();
  int d = tid >> 2, sp = tid & 3;
  bf16 tmp[16];
#pragma unroll
  for (int j = 0; j < 16; ++j) tmp[j] = t[sp * 16 + j][d];
  bf16* dst = vt + (size_t)((b * 16 + h) * 64 + d) * 2048 + st * 64 + sp * 16;
  *(bf16x8*)dst = *(bf16x8*)&tmp[0];
  *(bf16x8*)(dst + 8) = *(bf16x8*)&tmp[8];
}

// ---------------- bf16 GEMM 128x128 (QKV projection), K-pack fused epilogue ----------------
template <int OUT_BF16, int KFUSE>
__global__ __launch_bounds__(256) void gemm_bt_kernel(
    const bf16* __restrict__ A, const bf16* __restrict__ Bt,
    const float* __restrict__ bias, void* __restrict__ C,
    int M, int N, int K, int scale_cols, float scale_val,
    const int* __restrict__ rank, bf16* __restrict__ kp) {
  __shared__ __align__(16) bf16 As[128 * 64];
  __shared__ __align__(16) bf16 Bs[128 * 64];
  int bn = blockIdx.x * 128, bm = blockIdx.y * 128;
  int tid = threadIdx.x;
  int l = tid & 63;
  int w = tid >> 6;
  int wr = w >> 1, wc = w & 1;
  int g = l >> 4, c = l & 15;
  int swz = (c & 7) << 3;
  int srow = l >> 3;
  int scol = ((l & 7) ^ srow) << 3;
  const bf16* Ap = A + (size_t)(bm + w * 32 + srow) * K + scol;
  const bf16* Bp = Bt + (size_t)(bn + w * 32 + srow) * K + scol;
  bf16* AsW = As + w * 32 * 64;
  bf16* BsW = Bs + w * 32 * 64;

  f32x4 acc[4][4] = {};
  for (int k0 = 0; k0 < K; k0 += 64) {
    __syncthreads();
#pragma unroll
    for (int i = 0; i < 4; ++i) {
      gload16(Ap + (size_t)(8 * i) * K + k0, AsW + i * 512);
      gload16(Bp + (size_t)(8 * i) * K + k0, BsW + i * 512);
    }
    __syncthreads();
#pragma unroll
    for (int kh = 0; kh < 2; ++kh) {
      bf16x8 af[4], bfr[4];
#pragma unroll
      for (int m = 0; m < 4; ++m)
        af[m] = *(const bf16x8*)&As[(wr * 64 + m * 16 + c) * 64 + ((kh * 32 + g * 8) ^ swz)];
#pragma unroll
      for (int n = 0; n < 4; ++n)
        bfr[n] = *(const bf16x8*)&Bs[(wc * 64 + n * 16 + c) * 64 + ((kh * 32 + g * 8) ^ swz)];
#pragma unroll
      for (int m = 0; m < 4; ++m)
#pragma unroll
        for (int n = 0; n < 4; ++n)
          acc[m][n] = mfma16(af[m], bfr[n], acc[m][n]);
    }
  }
  int rowb = bm + wr * 64;
  int colb = bn + wc * 64;
#pragma unroll
  for (int n = 0; n < 4; ++n) {
    int col = colb + n * 16 + c;
    float bv = bias[col];
    float s = (col < scale_cols) ? scale_val : 1.0f;
    bool isk = KFUSE && (col >= 1024) && (col < 2048);
    int hh = (col >> 6) & 15;
    int dd = col & 63;
#pragma unroll
    for (int m = 0; m < 4; ++m) {
      int row = rowb + m * 16 + g * 4;
#pragma unroll
      for (int j = 0; j < 4; ++j) {
        float v = (acc[m][n][j] + bv) * s;
        if (OUT_BF16) {
          if (isk) {
            int rr = row + j;
            int ss = rank[rr & 2047];
            kp[((size_t)((rr >> 11) * 16 + hh) * 2048 + ss) * 64 + dd] = (bf16)v;
          } else {
            ((bf16*)C)[(size_t)(row + j) * N + col] = (bf16)v;
          }
        } else {
          ((float*)C)[(size_t)(row + j) * N + col] = v;
        }
      }
    }
  }
}

// ---------------- bf16 GEMM 64x128 tile (out-projection): grid (N/128, M/64) ----------------
__global__ __launch_bounds__(256) void gemm64_kernel(
    const bf16* __restrict__ A, const bf16* __restrict__ Bt,
    const float* __restrict__ bias, float* __restrict__ C,
    int M, int N, int K) {
  __shared__ __align__(16) bf16 As[64 * 64];
  __shared__ __align__(16) bf16 Bs[128 * 64];
  int bn = blockIdx.x * 128, bm = blockIdx.y * 64;
  int tid = threadIdx.x;
  int l = tid & 63;
  int w = tid >> 6;
  int g = l >> 4, c = l & 15;
  int swz = (c & 7) << 3;
  int srow = l >> 3;
  int scol = ((l & 7) ^ srow) << 3;
  const bf16* Ap = A + (size_t)(bm + w * 16 + srow) * K + scol;
  const bf16* Bp = Bt + (size_t)(bn + w * 32 + srow) * K + scol;
  bf16* AsW = As + w * 16 * 64;
  bf16* BsW = Bs + w * 32 * 64;

  f32x4 acc[4][2] = {};
  for (int k0 = 0; k0 < K; k0 += 64) {
    __syncthreads();
#pragma unroll
    for (int i = 0; i < 2; ++i)
      gload16(Ap + (size_t)(8 * i) * K + k0, AsW + i * 512);
#pragma unroll
    for (int i = 0; i < 4; ++i)
      gload16(Bp + (size_t)(8 * i) * K + k0, BsW + i * 512);
    __syncthreads();
#pragma unroll
    for (int kh = 0; kh < 2; ++kh) {
      int koff = (kh * 32 + g * 8) ^ swz;
      bf16x8 af[4], bfr[2];
#pragma unroll
      for (int m = 0; m < 4; ++m)
        af[m] = *(const bf16x8*)&As[(m * 16 + c) * 64 + koff];
#pragma unroll
      for (int n = 0; n < 2; ++n)
        bfr[n] = *(const bf16x8*)&Bs[(w * 32 + n * 16 + c) * 64 + koff];
#pragma unroll
      for (int m = 0; m < 4; ++m)
#pragma unroll
        for (int n = 0; n < 2; ++n)
          acc[m][n] = mfma16(af[m], bfr[n], acc[m][n]);
    }
  }
#pragma unroll
  for (int n = 0; n < 2; ++n) {
    int col = bn + w * 32 + n * 16 + c;
    float bv = bias[col];
#pragma unroll
    for (int m = 0; m < 4; ++m) {
      int row = bm + m * 16 + g * 4;
#pragma unroll
      for (int j = 0; j < 4; ++j)
        C[(size_t)(row + j) * N + col] = acc[m][n][j] + bv;
    }
  }
}

// ---------------- flash attention, T15-style pipelined: PV(t) overlaps QK/SM(t+1) ----------------
// R17-validated per-op compute (sorted keys, 32 q/wave, mirrored bias, MFMA-ones psum).
// Restructured schedule: each body does {barrier; STAGE(t+2); QK(t+1)+SM(t+1)->regs;
// PV(t); write Ps(t+1)}. PV(t) is independent of QK/SM(t+1) -> compiler interleaves
// (MFMA/DS under exp2 VALU). Single Ps (per-wave; write-after-read in program order,
// per-wave in-order DS + next barrier's lgkm drain guarantee visibility). K double-buffered,
// V TRIPLE-buffered (stage slot (t+2)%3 != read slot t%3). 1 barrier/tile, same as before.
__global__ __launch_bounds__(256) void attn_kernel(
    const bf16* __restrict__ qkv, const bf16* __restrict__ kp,
    const bf16* __restrict__ vt, const int* __restrict__ lag,
    const int* __restrict__ slag, const float* __restrict__ lag_bias,
    bf16* __restrict__ out) {
  __shared__ __align__(16) bf16 Ks0[64 * 64];
  __shared__ __align__(16) bf16 Ks1[64 * 64];
  __shared__ __align__(16) bf16 Vs0[64 * 64];
  __shared__ __align__(16) bf16 Vs1[64 * 64];
  __shared__ __align__(16) bf16 Vs2[64 * 64];
  __shared__ __align__(16) bf16 Ps[4][32][72];
  __shared__ float bias2_s[1028];
  __shared__ int lag_s[2048];   // sorted lag (keys)

  int blk = blockIdx.x;
  blk = (blk & 7) * 64 + (blk >> 3);  // bijective XCD swizzle (512 % 8 == 0)
  int qt = blk & 15;
  int h = (blk >> 4) & 15;
  int b = blk >> 8;
  int tid = threadIdx.x;
  int w = tid >> 6, l = tid & 63, g = l >> 4, c = l & 15;

  for (int i = tid; i < 1025; i += 256) {
    int d = i - 512;
    d = d < 0 ? -d : d;
    bias2_s[i] = lag_bias[h * 513 + d] * 1.44269504f;
  }
  for (int i = tid; i < 2048; i += 256) lag_s[i] = slag[i];

  int q0 = qt * 128 + w * 32;
  const bf16* qbase = qkv + (size_t)(b * 2048 + q0) * 3072 + h * 64;
  bf16x8 qf[2][2];
#pragma unroll
  for (int m = 0; m < 2; ++m)
#pragma unroll
    for (int kh = 0; kh < 2; ++kh)
      qf[m][kh] = *(const bf16x8*)(qbase + (size_t)(m * 16 + c) * 3072 + kh * 32 + g * 8);

  int lagq[2][4];
#pragma unroll
  for (int m = 0; m < 2; ++m)
#pragma unroll
    for (int j = 0; j < 4; ++j) lagq[m][j] = lag[q0 + m * 16 + g * 4 + j] + 512;

  bf16x8 ones8;
#pragma unroll
  for (int e = 0; e < 8; ++e) ones8[e] = (bf16)1.0f;

  int swz = (c & 7) << 3;
  int off0 = (g * 8) ^ swz;
  int off1 = off0 ^ 32;

  int r0 = w * 16 + (l >> 3);
  int colE = ((l & 7) ^ (l >> 3)) << 3;
  const bf16* kbase = kp + (size_t)(b * 16 + h) * 2048 * 64;
  const bf16* vbase = vt + (size_t)(b * 16 + h) * 64 * 2048;
  const bf16* kg0 = kbase + (size_t)r0 * 64 + colE;
  const bf16* kg1 = kbase + (size_t)(r0 + 8) * 64 + colE;
  const bf16* vg0 = vbase + (size_t)r0 * 2048 + colE;
  const bf16* vg1 = vbase + (size_t)(r0 + 8) * 2048 + colE;

#define STAGE(KD, VD)                    \
  do {                                   \
    gload16(kg0, KD + w * 1024);         \
    gload16(kg1, KD + w * 1024 + 512);   \
    gload16(vg0, VD + w * 1024);         \
    gload16(vg1, VD + w * 1024 + 512);   \
    kg0 += 64 * 64; kg1 += 64 * 64;      \
    vg0 += 64; vg1 += 64;                \
  } while (0)

  f32x4 oacc[2][4] = {};
  f32x4 psacc[2] = {};

// QK(T1) from KC + softmax into registers pr, then write Ps (order matters: used by BODYX)
#define QKSM(KC, T1, PRR)                                                         \
  do {                                                                            \
    f32x4 sf[2][4] = {};                                                          \
    int lagk[4];                                                                  \
    _Pragma("unroll") for (int kb = 0; kb < 4; ++kb) {                            \
      int row = kb * 16 + c;                                                      \
      bf16x8 k0 = *(const bf16x8*)&KC[row * 64 + off0];                           \
      bf16x8 k1 = *(const bf16x8*)&KC[row * 64 + off1];                           \
      sf[0][kb] = mfma16(qf[0][0], k0, sf[0][kb]);                                \
      sf[0][kb] = mfma16(qf[0][1], k1, sf[0][kb]);                                \
      sf[1][kb] = mfma16(qf[1][0], k0, sf[1][kb]);                                \
      sf[1][kb] = mfma16(qf[1][1], k1, sf[1][kb]);                                \
      lagk[kb] = lag_s[(T1) * 64 + kb * 16 + c];                                  \
    }                                                                             \
    _Pragma("unroll") for (int m = 0; m < 2; ++m)                                 \
    _Pragma("unroll") for (int kb = 0; kb < 4; ++kb)                              \
    _Pragma("unroll") for (int j = 0; j < 4; ++j) {                               \
      int ld = lagq[m][j] - lagk[kb];                                             \
      PRR[m][kb * 4 + j] = __builtin_amdgcn_exp2f(sf[m][kb][j] + bias2_s[ld]);    \
    }                                                                             \
  } while (0)

#define PSWRITE(PRR)                                                              \
  do {                                                                            \
    _Pragma("unroll") for (int m = 0; m < 2; ++m)                                 \
    _Pragma("unroll") for (int kb = 0; kb < 4; ++kb)                              \
    _Pragma("unroll") for (int j = 0; j < 4; ++j)                                 \
      Ps[w][m * 16 + g * 4 + j][kb * 16 + c] = (bf16)PRR[m][kb * 4 + j];          \
  } while (0)

#define PVSTEP(VR)                                                                \
  do {                                                                            \
    _Pragma("unroll") for (int ph = 0; ph < 2; ++ph) {                            \
      bf16x8 pa0 = *(const bf16x8*)&Ps[w][c][ph * 32 + g * 8];                    \
      bf16x8 pa1 = *(const bf16x8*)&Ps[w][16 + c][ph * 32 + g * 8];               \
      int voff = ph ? off1 : off0;                                                \
      _Pragma("unroll") for (int n = 0; n < 4; ++n) {                             \
        bf16x8 vf = *(const bf16x8*)&VR[(n * 16 + c) * 64 + voff];                \
        oacc[0][n] = mfma16(pa0, vf, oacc[0][n]);                                 \
        oacc[1][n] = mfma16(pa1, vf, oacc[1][n]);                                 \
      }                                                                           \
      psacc[0] = mfma16(pa0, ones8, psacc[0]);                                    \
      psacc[1] = mfma16(pa1, ones8, psacc[1]);                                    \
    }                                                                             \
  } while (0)

// body t: stage(t+2), QK/SM(t+1) -> regs, PV(t) from Ps+VR, then write Ps(t+1)
#define BODYX(KC, KS, VR, VS, T1, DOSTAGE)                                        \
  do {                                                                            \
    __syncthreads();                                                              \
    if (DOSTAGE) { STAGE(KS, VS); }                                               \
    float pr[2][16];                                                              \
    QKSM(KC, T1, pr);                                                             \
    PVSTEP(VR);                                                                   \
    PSWRITE(pr);                                                                  \
  } while (0)

  // prologue: stage tiles 0,1; QK/SM(0) -> Ps
  STAGE(Ks0, Vs0);
  __syncthreads();   // bias2_s/lag_s + tile0 staged
  STAGE(Ks1, Vs1);
  {
    float pr[2][16];
    QKSM(Ks0, 0, pr);
    PSWRITE(pr);
  }

  // bodies t=0..29 (stage t+2, compute QK/SM(t+1), PV(t)); period 6 = LCM(K:2, V:3)
  for (int tb = 0; tb < 30; tb += 6) {
    BODYX(Ks1, Ks0, Vs0, Vs2, tb + 1, 1);
    BODYX(Ks0, Ks1, Vs1, Vs0, tb + 2, 1);
    BODYX(Ks1, Ks0, Vs2, Vs1, tb + 3, 1);
    BODYX(Ks0, Ks1, Vs0, Vs2, tb + 4, 1);
    BODYX(Ks1, Ks0, Vs1, Vs0, tb + 5, 1);
    BODYX(Ks0, Ks1, Vs2, Vs1, tb + 6, 1);
  }
  // tail t=30: QK/SM(31), PV(30), no stage
  BODYX(Ks1, Ks0, Vs0, Vs2, 31, 0);
  // final PV(31) (Ps written just above by same wave; drain for safety)
  asm volatile("s_waitcnt lgkmcnt(0)" ::: "memory");
  PVSTEP(Vs1);

  // normalize + store (psacc holds full row sums, replicated over c-lanes)
#pragma unroll
  for (int m = 0; m < 2; ++m) {
#pragma unroll
    for (int j = 0; j < 4; ++j) {
      float inv = 1.f / psacc[m][j];
      bf16* ob = out + (size_t)(b * 2048 + q0 + m * 16 + g * 4 + j) * 1024 + h * 64;
#pragma unroll
      for (int n = 0; n < 4; ++n)
        ob[n * 16 + c] = (bf16)(oacc[m][n][j] * inv);
    }
  }
#undef STAGE
#undef QKSM
#undef PSWRITE
#undef PVSTEP
#undef BODYX
}

extern "C" void kernel_launch(void* const* d_in, const int* in_sizes, int n_in,
                              void* d_out, int out_size, void* d_ws, size_t ws_size,
                              hipStream_t stream) {
  const float* x        = (const float*)d_in[0];
  const int*   lag      = (const int*)d_in[1];
  const float* wq       = (const float*)d_in[2];
  const float* bq       = (const float*)d_in[3];
  const float* wk       = (const float*)d_in[4];
  const float* bk       = (const float*)d_in[5];
  const float* wv       = (const float*)d_in[6];
  const float* bv       = (const float*)d_in[7];
  const float* wo       = (const float*)d_in[8];
  const float* bo       = (const float*)d_in[9];
  const float* lag_bias = (const float*)d_in[10];

  char* ws = (char*)d_ws;
  bf16*  xb    = (bf16*)ws;
  bf16*  wqkvt = (bf16*)(ws + (8u  << 20));
  bf16*  wot   = (bf16*)(ws + (14u << 20));
  float* bqkv  = (float*)(ws + (16u << 20));
  int*   perm  = (int*)(ws + (16u << 20) + 32768);
  int*   slag  = (int*)(ws + (16u << 20) + 65536);
  int*   rankp = (int*)(ws + (16u << 20) + 98304);
  bf16*  qkv   = (bf16*)(ws + (17u << 20));
  bf16*  vtb   = (bf16*)(ws + (41u << 20));
  bf16*  kpk   = (bf16*)(ws + (49u << 20));
  bf16*  aout  = xb;  // attn output reuses xb (dead after QKV GEMM)

  prep_kernel<<<3148, 256, 0, stream>>>(x, wq, wk, wv, wo, bq, bk, bv, lag,
                                        xb, wqkvt, wot, bqkv, perm, slag, rankp);
  gemm_bt_kernel<1, 1><<<dim3(24, 32), 256, 0, stream>>>(
      xb, wqkvt, bqkv, qkv, 4096, 3072, 1024, 1024, 0.125f * 1.44269504f, rankp, kpk);
  transpose_v_kernel<<<1024, 256, 0, stream>>>(qkv, perm, vtb);
  attn_kernel<<<512, 256, 0, stream>>>(qkv, kpk, vtb, lag, slag, lag_bias, aout);
  gemm64_kernel<<<dim3(8, 64), 256, 0, stream>>>(
      aout, wot, bo, (float*)d_out, 4096, 1024, 1024);
}

// Round 19
// 152.370 us; speedup vs baseline: 1.0637x; 1.0637x over previous
//
#include <hip/hip_runtime.h>

typedef __bf16 bf16;
typedef __bf16 bf16x8 __attribute__((ext_vector_type(8)));
typedef float f32x4 __attribute__((ext_vector_type(4)));

__device__ __forceinline__ f32x4 mfma16(bf16x8 a, bf16x8 b, f32x4 c) {
  return __builtin_amdgcn_mfma_f32_16x16x32_bf16(a, b, c, 0, 0, 0);
}
__device__ __forceinline__ void gload16(const bf16* g, bf16* l) {
  __builtin_amdgcn_global_load_lds((const __attribute__((address_space(1))) unsigned int*)g,
                                   (__attribute__((address_space(3))) unsigned int*)l, 16, 0, 0);
}

// ------- fused prep: x f32->bf16 (0..2047), weight transpose (2048..3071),
//         bias concat (3072..3083), lag rank-sort (3084..3147). grid 3148 -------
__global__ __launch_bounds__(256) void prep_kernel(
    const float* __restrict__ x, const float* __restrict__ wq,
    const float* __restrict__ wk, const float* __restrict__ wv,
    const float* __restrict__ wo, const float* __restrict__ bq,
    const float* __restrict__ bk, const float* __restrict__ bv,
    const int* __restrict__ lag,
    bf16* __restrict__ xb, bf16* __restrict__ wqkvt, bf16* __restrict__ wot,
    float* __restrict__ bqkv, int* __restrict__ perm, int* __restrict__ slag,
    int* __restrict__ rank) {
  int blk = blockIdx.x;
  int tid = threadIdx.x;
  if (blk < 2048) {
    int i = blk * 256 + tid;
    const float4* p = (const float4*)x + (size_t)i * 2;
    float4 f0 = p[0], f1 = p[1];
    bf16x8 o;
    o[0] = (bf16)f0.x; o[1] = (bf16)f0.y; o[2] = (bf16)f0.z; o[3] = (bf16)f0.w;
    o[4] = (bf16)f1.x; o[5] = (bf16)f1.y; o[6] = (bf16)f1.z; o[7] = (bf16)f1.w;
    *((bf16x8*)xb + i) = o;
    return;
  }
  if (blk >= 3084) {
    __shared__ int l[2048];
    for (int i = tid; i < 2048; i += 256) l[i] = lag[i];
    __syncthreads();
    int i = (blk - 3084) * 32 + (tid >> 3);
    int s = tid & 7;
    int vi = l[i];
    int cnt = 0;
    for (int j = s * 256; j < s * 256 + 256; j += 4) {
      int4 vj = *(const int4*)&l[j];
      cnt += (vj.x < vi || (vj.x == vi && (j + 0) < i));
      cnt += (vj.y < vi || (vj.y == vi && (j + 1) < i));
      cnt += (vj.z < vi || (vj.z == vi && (j + 2) < i));
      cnt += (vj.w < vi || (vj.w == vi && (j + 3) < i));
    }
    cnt += __shfl_xor(cnt, 1);
    cnt += __shfl_xor(cnt, 2);
    cnt += __shfl_xor(cnt, 4);
    if (s == 0) { perm[cnt] = i; slag[cnt] = vi; rank[i] = cnt; }
    return;
  }
  if (blk >= 3072) {
    int i = (blk - 3072) * 256 + tid;
    if (i < 1024) bqkv[i] = bq[i];
    else if (i < 2048) bqkv[i] = bk[i - 1024];
    else if (i < 3072) bqkv[i] = bv[i - 2048];
    return;
  }
  __shared__ float t[64][68];
  int sub = blk - 2048;
  int wsel = sub >> 8;
  sub &= 255;
  const float* in = wsel == 0 ? wq : wsel == 1 ? wk : wsel == 2 ? wv : wo;
  bf16* out = (wsel == 3) ? wot : (wqkvt + (size_t)wsel * (1u << 20));
  int bx = sub & 15;
  int by = sub >> 4;
  int r = tid >> 2, p = tid & 3;
  const float* src = in + (size_t)(by * 64 + r) * 1024 + bx * 64 + p * 16;
#pragma unroll
  for (int j = 0; j < 16; j += 4)
    *(float4*)&t[r][p * 16 + j] = *(const float4*)(src + j);
  __syncthreads();
  int n = tid >> 2, sp = tid & 3;
  bf16 tmp[16];
#pragma unroll
  for (int j = 0; j < 16; ++j) tmp[j] = (bf16)t[sp * 16 + j][n];
  bf16* dst = out + (size_t)(bx * 64 + n) * 1024 + by * 64 + sp * 16;
  *(bf16x8*)dst = *(bf16x8*)&tmp[0];
  *(bf16x8*)(dst + 8) = *(bf16x8*)&tmp[8];
}

// ---- V transpose sorted: vt[(b*16+h)*64 + d][ss] = V[b][perm[ss]][h*64+d] ----
__global__ __launch_bounds__(256) void transpose_v_kernel(const bf16* __restrict__ qkv,
                                                          const int* __restrict__ perm,
                                                          bf16* __restrict__ vt) {
  __shared__ bf16 t[64][72];
  int blk = blockIdx.x;
  int st = blk & 31, h = (blk >> 5) & 15, b = blk >> 9;
  int tid = threadIdx.x;
  int r = tid >> 2, p = tid & 3;
  int src_s = perm[st * 64 + r];
  const bf16* src = qkv + (size_t)(b * 2048 + src_s) * 3072 + 2048 + h * 64 + p * 16;
  *(bf16x8*)&t[r][p * 16] = *(const bf16x8*)src;
  *(bf16x8*)&t[r][p * 16 + 8] = *(const bf16x8*)(src + 8);
  __syncthreads();
  int d = tid >> 2, sp = tid & 3;
  bf16 tmp[16];
#pragma unroll
  for (int j = 0; j < 16; ++j) tmp[j] = t[sp * 16 + j][d];
  bf16* dst = vt + (size_t)((b * 16 + h) * 64 + d) * 2048 + st * 64 + sp * 16;
  *(bf16x8*)dst = *(bf16x8*)&tmp[0];
  *(bf16x8*)(dst + 8) = *(bf16x8*)&tmp[8];
}

// ---------------- bf16 GEMM 128x128 (QKV projection), K-pack fused epilogue ----------------
template <int OUT_BF16, int KFUSE>
__global__ __launch_bounds__(256) void gemm_bt_kernel(
    const bf16* __restrict__ A, const bf16* __restrict__ Bt,
    const float* __restrict__ bias, void* __restrict__ C,
    int M, int N, int K, int scale_cols, float scale_val,
    const int* __restrict__ rank, bf16* __restrict__ kp) {
  __shared__ __align__(16) bf16 As[128 * 64];
  __shared__ __align__(16) bf16 Bs[128 * 64];
  int bn = blockIdx.x * 128, bm = blockIdx.y * 128;
  int tid = threadIdx.x;
  int l = tid & 63;
  int w = tid >> 6;
  int wr = w >> 1, wc = w & 1;
  int g = l >> 4, c = l & 15;
  int swz = (c & 7) << 3;
  int srow = l >> 3;
  int scol = ((l & 7) ^ srow) << 3;
  const bf16* Ap = A + (size_t)(bm + w * 32 + srow) * K + scol;
  const bf16* Bp = Bt + (size_t)(bn + w * 32 + srow) * K + scol;
  bf16* AsW = As + w * 32 * 64;
  bf16* BsW = Bs + w * 32 * 64;

  f32x4 acc[4][4] = {};
  for (int k0 = 0; k0 < K; k0 += 64) {
    __syncthreads();
#pragma unroll
    for (int i = 0; i < 4; ++i) {
      gload16(Ap + (size_t)(8 * i) * K + k0, AsW + i * 512);
      gload16(Bp + (size_t)(8 * i) * K + k0, BsW + i * 512);
    }
    __syncthreads();
#pragma unroll
    for (int kh = 0; kh < 2; ++kh) {
      bf16x8 af[4], bfr[4];
#pragma unroll
      for (int m = 0; m < 4; ++m)
        af[m] = *(const bf16x8*)&As[(wr * 64 + m * 16 + c) * 64 + ((kh * 32 + g * 8) ^ swz)];
#pragma unroll
      for (int n = 0; n < 4; ++n)
        bfr[n] = *(const bf16x8*)&Bs[(wc * 64 + n * 16 + c) * 64 + ((kh * 32 + g * 8) ^ swz)];
#pragma unroll
      for (int m = 0; m < 4; ++m)
#pragma unroll
        for (int n = 0; n < 4; ++n)
          acc[m][n] = mfma16(af[m], bfr[n], acc[m][n]);
    }
  }
  int rowb = bm + wr * 64;
  int colb = bn + wc * 64;
#pragma unroll
  for (int n = 0; n < 4; ++n) {
    int col = colb + n * 16 + c;
    float bv = bias[col];
    float s = (col < scale_cols) ? scale_val : 1.0f;
    bool isk = KFUSE && (col >= 1024) && (col < 2048);
    int hh = (col >> 6) & 15;
    int dd = col & 63;
#pragma unroll
    for (int m = 0; m < 4; ++m) {
      int row = rowb + m * 16 + g * 4;
#pragma unroll
      for (int j = 0; j < 4; ++j) {
        float v = (acc[m][n][j] + bv) * s;
        if (OUT_BF16) {
          if (isk) {
            int rr = row + j;
            int ss = rank[rr & 2047];
            kp[((size_t)((rr >> 11) * 16 + hh) * 2048 + ss) * 64 + dd] = (bf16)v;
          } else {
            ((bf16*)C)[(size_t)(row + j) * N + col] = (bf16)v;
          }
        } else {
          ((float*)C)[(size_t)(row + j) * N + col] = v;
        }
      }
    }
  }
}

// ---------------- bf16 GEMM 64x64 tile (out-projection): grid (N/64, M/64) = (16,64) ----------------
// 1024 blocks = 4 blocks/CU for write-latency hiding. 4 waves split by column (16 each).
__global__ __launch_bounds__(256) void gemm64_kernel(
    const bf16* __restrict__ A, const bf16* __restrict__ Bt,
    const float* __restrict__ bias, float* __restrict__ C,
    int M, int N, int K) {
  __shared__ __align__(16) bf16 As[64 * 64];
  __shared__ __align__(16) bf16 Bs[64 * 64];
  int bn = blockIdx.x * 64, bm = blockIdx.y * 64;
  int tid = threadIdx.x;
  int l = tid & 63;
  int w = tid >> 6;
  int g = l >> 4, c = l & 15;
  int swz = (c & 7) << 3;
  int srow = w * 16 + (l >> 3);            // wave w stages rows w*16..w*16+15 (two 8-row chunks)
  int scol = ((l & 7) ^ (l >> 3)) << 3;
  const bf16* Ap = A + (size_t)(bm + srow) * K + scol;
  const bf16* Bp = Bt + (size_t)(bn + srow) * K + scol;
  bf16* AsW = As + w * 1024;
  bf16* BsW = Bs + w * 1024;

  f32x4 acc[4] = {};
  for (int k0 = 0; k0 < K; k0 += 64) {
    __syncthreads();
    gload16(Ap + k0, AsW);
    gload16(Ap + (size_t)8 * K + k0, AsW + 512);
    gload16(Bp + k0, BsW);
    gload16(Bp + (size_t)8 * K + k0, BsW + 512);
    __syncthreads();
#pragma unroll
    for (int kh = 0; kh < 2; ++kh) {
      int koff = (kh * 32 + g * 8) ^ swz;
      bf16x8 bfr = *(const bf16x8*)&Bs[(w * 16 + c) * 64 + koff];
#pragma unroll
      for (int m = 0; m < 4; ++m) {
        bf16x8 af = *(const bf16x8*)&As[(m * 16 + c) * 64 + koff];
        acc[m] = mfma16(af, bfr, acc[m]);
      }
    }
  }
  int col = bn + w * 16 + c;
  float bv = bias[col];
#pragma unroll
  for (int m = 0; m < 4; ++m) {
    int row = bm + m * 16 + g * 4;
#pragma unroll
    for (int j = 0; j < 4; ++j)
      C[(size_t)(row + j) * N + col] = acc[m][j] + bv;
  }
}

// ---------------- flash attention (R17-validated: sorted keys, 32 q/wave, mirrored bias,
//                  MFMA-ones psum, LDS bias gathers, distinct-LDS double buffer) ----------------
__global__ __launch_bounds__(256) void attn_kernel(
    const bf16* __restrict__ qkv, const bf16* __restrict__ kp,
    const bf16* __restrict__ vt, const int* __restrict__ lag,
    const int* __restrict__ slag, const float* __restrict__ lag_bias,
    bf16* __restrict__ out) {
  __shared__ __align__(16) bf16 Ks0[64 * 64];
  __shared__ __align__(16) bf16 Vs0[64 * 64];
  __shared__ __align__(16) bf16 Ks1[64 * 64];
  __shared__ __align__(16) bf16 Vs1[64 * 64];
  __shared__ __align__(16) bf16 Ps[4][32][72];
  __shared__ float bias2_s[1028];
  __shared__ int lag_s[2048];   // sorted lag (keys)

  int blk = blockIdx.x;
  blk = (blk & 7) * 64 + (blk >> 3);  // bijective XCD swizzle (512 % 8 == 0)
  int qt = blk & 15;
  int h = (blk >> 4) & 15;
  int b = blk >> 8;
  int tid = threadIdx.x;
  int w = tid >> 6, l = tid & 63, g = l >> 4, c = l & 15;

  for (int i = tid; i < 1025; i += 256) {
    int d = i - 512;
    d = d < 0 ? -d : d;
    bias2_s[i] = lag_bias[h * 513 + d] * 1.44269504f;
  }
  for (int i = tid; i < 2048; i += 256) lag_s[i] = slag[i];

  int q0 = qt * 128 + w * 32;
  const bf16* qbase = qkv + (size_t)(b * 2048 + q0) * 3072 + h * 64;
  bf16x8 qf[2][2];
#pragma unroll
  for (int m = 0; m < 2; ++m)
#pragma unroll
    for (int kh = 0; kh < 2; ++kh)
      qf[m][kh] = *(const bf16x8*)(qbase + (size_t)(m * 16 + c) * 3072 + kh * 32 + g * 8);

  int lagq[2][4];
#pragma unroll
  for (int m = 0; m < 2; ++m)
#pragma unroll
    for (int j = 0; j < 4; ++j) lagq[m][j] = lag[q0 + m * 16 + g * 4 + j] + 512;

  bf16x8 ones8;
#pragma unroll
  for (int e = 0; e < 8; ++e) ones8[e] = (bf16)1.0f;

  int swz = (c & 7) << 3;
  int off0 = (g * 8) ^ swz;
  int off1 = off0 ^ 32;

  int r0 = w * 16 + (l >> 3);
  int colE = ((l & 7) ^ (l >> 3)) << 3;
  const bf16* kbase = kp + (size_t)(b * 16 + h) * 2048 * 64;
  const bf16* vbase = vt + (size_t)(b * 16 + h) * 64 * 2048;
  const bf16* kg0 = kbase + (size_t)r0 * 64 + colE;
  const bf16* kg1 = kbase + (size_t)(r0 + 8) * 64 + colE;
  const bf16* vg0 = vbase + (size_t)r0 * 2048 + colE;
  const bf16* vg1 = vbase + (size_t)(r0 + 8) * 2048 + colE;

#define STAGE(KD, VD)                    \
  do {                                   \
    gload16(kg0, KD + w * 1024);         \
    gload16(kg1, KD + w * 1024 + 512);   \
    gload16(vg0, VD + w * 1024);         \
    gload16(vg1, VD + w * 1024 + 512);   \
    kg0 += 64 * 64; kg1 += 64 * 64;      \
    vg0 += 64; vg1 += 64;                \
  } while (0)

  STAGE(Ks0, Vs0);
  __syncthreads();

  f32x4 oacc[2][4] = {};
  f32x4 psacc[2] = {};

#define TILE(KB, VB, KT)                                                          \
  do {                                                                            \
    f32x4 sf[2][4] = {};                                                          \
    int lagk[4];                                                                  \
    _Pragma("unroll") for (int kb = 0; kb < 4; ++kb) {                            \
      int row = kb * 16 + c;                                                      \
      bf16x8 k0 = *(const bf16x8*)&KB[row * 64 + off0];                           \
      bf16x8 k1 = *(const bf16x8*)&KB[row * 64 + off1];                           \
      sf[0][kb] = mfma16(qf[0][0], k0, sf[0][kb]);                                \
      sf[0][kb] = mfma16(qf[0][1], k1, sf[0][kb]);                                \
      sf[1][kb] = mfma16(qf[1][0], k0, sf[1][kb]);                                \
      sf[1][kb] = mfma16(qf[1][1], k1, sf[1][kb]);                                \
      lagk[kb] = lag_s[(KT) + kb * 16 + c];                                       \
    }                                                                             \
    _Pragma("unroll") for (int m = 0; m < 2; ++m)                                 \
    _Pragma("unroll") for (int kb = 0; kb < 4; ++kb)                              \
    _Pragma("unroll") for (int j = 0; j < 4; ++j) {                               \
      int ld = lagq[m][j] - lagk[kb];                                             \
      float p = __builtin_amdgcn_exp2f(sf[m][kb][j] + bias2_s[ld]);               \
      Ps[w][m * 16 + g * 4 + j][kb * 16 + c] = (bf16)p;                           \
    }                                                                             \
    asm volatile("s_waitcnt lgkmcnt(0)" ::: "memory");                            \
    _Pragma("unroll") for (int ph = 0; ph < 2; ++ph) {                            \
      bf16x8 pa0 = *(const bf16x8*)&Ps[w][c][ph * 32 + g * 8];                    \
      bf16x8 pa1 = *(const bf16x8*)&Ps[w][16 + c][ph * 32 + g * 8];               \
      int voff = ph ? off1 : off0;                                                \
      _Pragma("unroll") for (int n = 0; n < 4; ++n) {                             \
        bf16x8 vf = *(const bf16x8*)&VB[(n * 16 + c) * 64 + voff];                \
        oacc[0][n] = mfma16(pa0, vf, oacc[0][n]);                                 \
        oacc[1][n] = mfma16(pa1, vf, oacc[1][n]);                                 \
      }                                                                           \
      psacc[0] = mfma16(pa0, ones8, psacc[0]);                                    \
      psacc[1] = mfma16(pa1, ones8, psacc[1]);                                    \
    }                                                                             \
  } while (0)

  for (int kt = 0; kt < 2048; kt += 128) {
    if (kt + 64 < 2048) STAGE(Ks1, Vs1);
    TILE(Ks0, Vs0, kt);
    __syncthreads();  // drains vmcnt: Ks1/Vs1 ready; closes Ks0/Vs0 reads
    if (kt + 128 < 2048) STAGE(Ks0, Vs0);
    TILE(Ks1, Vs1, kt + 64);
    __syncthreads();
  }

  // normalize + store (psacc holds full row sums, replicated over c-lanes)
#pragma unroll
  for (int m = 0; m < 2; ++m) {
#pragma unroll
    for (int j = 0; j < 4; ++j) {
      float inv = 1.f / psacc[m][j];
      bf16* ob = out + (size_t)(b * 2048 + q0 + m * 16 + g * 4 + j) * 1024 + h * 64;
#pragma unroll
      for (int n = 0; n < 4; ++n)
        ob[n * 16 + c] = (bf16)(oacc[m][n][j] * inv);
    }
  }
#undef STAGE
#undef TILE
}

extern "C" void kernel_launch(void* const* d_in, const int* in_sizes, int n_in,
                              void* d_out, int out_size, void* d_ws, size_t ws_size,
                              hipStream_t stream) {
  const float* x        = (const float*)d_in[0];
  const int*   lag      = (const int*)d_in[1];
  const float* wq       = (const float*)d_in[2];
  const float* bq       = (const float*)d_in[3];
  const float* wk       = (const float*)d_in[4];
  const float* bk       = (const float*)d_in[5];
  const float* wv       = (const float*)d_in[6];
  const float* bv       = (const float*)d_in[7];
  const float* wo       = (const float*)d_in[8];
  const float* bo       = (const float*)d_in[9];
  const float* lag_bias = (const float*)d_in[10];

  char* ws = (char*)d_ws;
  bf16*  xb    = (bf16*)ws;
  bf16*  wqkvt = (bf16*)(ws + (8u  << 20));
  bf16*  wot   = (bf16*)(ws + (14u << 20));
  float* bqkv  = (float*)(ws + (16u << 20));
  int*   perm  = (int*)(ws + (16u << 20) + 32768);
  int*   slag  = (int*)(ws + (16u << 20) + 65536);
  int*   rankp = (int*)(ws + (16u << 20) + 98304);
  bf16*  qkv   = (bf16*)(ws + (17u << 20));
  bf16*  vtb   = (bf16*)(ws + (41u << 20));
  bf16*  kpk   = (bf16*)(ws + (49u << 20));
  bf16*  aout  = xb;  // attn output reuses xb (dead after QKV GEMM)

  prep_kernel<<<3148, 256, 0, stream>>>(x, wq, wk, wv, wo, bq, bk, bv, lag,
                                        xb, wqkvt, wot, bqkv, perm, slag, rankp);
  gemm_bt_kernel<1, 1><<<dim3(24, 32), 256, 0, stream>>>(
      xb, wqkvt, bqkv, qkv, 4096, 3072, 1024, 1024, 0.125f * 1.44269504f, rankp, kpk);
  transpose_v_kernel<<<1024, 256, 0, stream>>>(qkv, perm, vtb);
  attn_kernel<<<512, 256, 0, stream>>>(qkv, kpk, vtb, lag, slag, lag_bias, aout);
  gemm64_kernel<<<dim3(16, 64), 256, 0, stream>>>(
      aout, wot, bo, (float*)d_out, 4096, 1024, 1024);
}